// Round 6
// baseline (338.417 us; speedup 1.0000x reference)
//
#include <hip/hip_runtime.h>
#include <hip/hip_bf16.h>

typedef __bf16 bf16;
typedef __bf16 bf16x4 __attribute__((ext_vector_type(4)));
typedef __bf16 bf16x8 __attribute__((ext_vector_type(8)));
typedef float f32x4 __attribute__((ext_vector_type(4)));

#define B_  32
#define C_  256
#define N_  1024
#define G_  8
#define CG_ 32
#define O3_ 768

// LDS XOR swizzles (element-index form). 8-element (16B) chunks preserved.
// 512B rows (256 bf16/row): slot(5b) ^= row&15
#define SWZ9(el) ((el) ^ ((((el) >> 8) & 15) << 3))
// 128B rows (64 bf16/row): slot(3b) ^= row&7
#define SWZ7(el) ((el) ^ ((((el) >> 6) & 7) << 3))

// async global->LDS, 16B per lane. LDS dest must be wave-uniform base (lanes
// auto-scatter base + lane*16); global src is per-lane.
#define GLOAD16(gp, lp)                                                        \
    __builtin_amdgcn_global_load_lds(                                          \
        (const __attribute__((address_space(1))) void*)(gp),                   \
        (__attribute__((address_space(3))) void*)(lp), 16, 0, 0)

// ---------------- kernel 0: weights f32 -> bf16 ----------------
__global__ __launch_bounds__(256) void k_convert(const float* __restrict__ qkv_w,
                                                 const float* __restrict__ out_w,
                                                 bf16* __restrict__ qkv_wh,
                                                 bf16* __restrict__ out_wh) {
    int i = blockIdx.x * 256 + threadIdx.x;
    if (i < O3_ * C_) qkv_wh[i] = (bf16)qkv_w[i];
    if (i < C_ * C_)  out_wh[i] = (bf16)out_w[i];
}

// ---------------- kernel 1: group norm (float4 vectorized) ----------------
__global__ __launch_bounds__(256) void k_gn(const float* __restrict__ x,
                                            const float* __restrict__ w,
                                            const float* __restrict__ bia,
                                            bf16* __restrict__ xn,
                                            bf16* __restrict__ xt) {
    int bg = blockIdx.x;
    int b = bg >> 3, g = bg & 7;
    const float4* xb4 = (const float4*)(x + (size_t)b * C_ * N_ + (size_t)g * CG_ * N_);
    int tid = threadIdx.x;

    float s = 0.f, ss = 0.f;
    for (int i = tid; i < CG_ * N_ / 4; i += 256) {
        float4 v = xb4[i];
        s  += v.x + v.y + v.z + v.w;
        ss += v.x * v.x + v.y * v.y + v.z * v.z + v.w * v.w;
    }
    for (int off = 32; off; off >>= 1) {
        s  += __shfl_down(s, off);
        ss += __shfl_down(ss, off);
    }
    __shared__ float red[8];
    __shared__ float stat[2];
    int wid = tid >> 6, lane = tid & 63;
    if (lane == 0) { red[wid] = s; red[wid + 4] = ss; }
    __syncthreads();
    if (tid == 0) {
        float S  = red[0] + red[1] + red[2] + red[3];
        float SS = red[4] + red[5] + red[6] + red[7];
        float mu = S / (float)(CG_ * N_);
        float var = SS / (float)(CG_ * N_) - mu * mu;
        stat[0] = mu;
        stat[1] = rsqrtf(var + 1e-5f);
    }
    __syncthreads();
    float mu = stat[0], rstd = stat[1];

    __shared__ bf16 tile[256][CG_ + 8];
    for (int nc = 0; nc < N_; nc += 256) {
        for (int i = tid; i < 2048; i += 256) {
            int cl = i >> 6, f = i & 63;
            int c = g * CG_ + cl;
            float sc = rstd * w[c], sh = bia[c] - mu * sc;
            float4 v = xb4[(size_t)cl * 256 + (nc >> 2) + f];
            bf16x4 h = { (bf16)(v.x * sc + sh), (bf16)(v.y * sc + sh),
                         (bf16)(v.z * sc + sh), (bf16)(v.w * sc + sh) };
            *(bf16x4*)(xn + (size_t)b * C_ * N_ + (size_t)c * N_ + nc + f * 4) = h;
            tile[f * 4 + 0][cl] = h[0];
            tile[f * 4 + 1][cl] = h[1];
            tile[f * 4 + 2][cl] = h[2];
            tile[f * 4 + 3][cl] = h[3];
        }
        __syncthreads();
        for (int u = tid; u < 256 * 4; u += 256) {
            int nl = u >> 2, ch = u & 3;
            bf16x8 v = *(const bf16x8*)&tile[nl][ch * 8];
            *(bf16x8*)(xt + (size_t)b * N_ * C_ + (size_t)(nc + nl) * C_ + g * CG_ + ch * 8) = v;
        }
        __syncthreads();
    }
}

// ---------------- kernel 2: QKV GEMM ----------------
__global__ __launch_bounds__(256) void k_qkv(const bf16* __restrict__ xt,
                                             const bf16* __restrict__ wq,
                                             const float* __restrict__ qb,
                                             bf16* __restrict__ Qs,
                                             bf16* __restrict__ Kt,
                                             bf16* __restrict__ Vt) {
    __shared__ bf16 smem[17408];
    bf16* aT = smem;                      // [128][64], swizzled
    bf16* bT = smem + 8192;               // [128][64], swizzled
    int nt = blockIdx.x, ot = blockIdx.y, b = blockIdx.z;
    int tid = threadIdx.x, wid = tid >> 6, lane = tid & 63;
    int wr = wid >> 1, wc = wid & 1;
    const bf16* Ab = xt + (size_t)b * N_ * C_ + (size_t)nt * 128 * C_;
    const bf16* Bb = wq + (size_t)ot * 128 * C_;

    bf16x8 areg[4], breg[4];
    #define LOAD_KT(kt)                                                        \
        for (int j = 0; j < 4; ++j) {                                          \
            int lin = (j * 256 + tid) * 8;                                     \
            int row = lin >> 6, col = lin & 63;                                \
            areg[j] = *(const bf16x8*)&Ab[(size_t)row * C_ + (kt) * 64 + col]; \
            breg[j] = *(const bf16x8*)&Bb[(size_t)row * C_ + (kt) * 64 + col]; \
        }

    f32x4 acc[4][4] = {};
    LOAD_KT(0);
    for (int kt = 0; kt < 4; ++kt) {
        for (int j = 0; j < 4; ++j) {
            int lin = (j * 256 + tid) * 8;
            *(bf16x8*)&aT[SWZ7(lin)] = areg[j];
            *(bf16x8*)&bT[SWZ7(lin)] = breg[j];
        }
        __syncthreads();
        if (kt < 3) { LOAD_KT(kt + 1); }
        for (int kk = 0; kk < 2; ++kk) {
            bf16x8 af[4], bfr[4];
            for (int m = 0; m < 4; ++m) {
                int el = (wr * 64 + m * 16 + (lane & 15)) * 64 + kk * 32 + (lane >> 4) * 8;
                af[m] = *(const bf16x8*)&aT[SWZ7(el)];
            }
            for (int n = 0; n < 4; ++n) {
                int el = (wc * 64 + n * 16 + (lane & 15)) * 64 + kk * 32 + (lane >> 4) * 8;
                bfr[n] = *(const bf16x8*)&bT[SWZ7(el)];
            }
            for (int m = 0; m < 4; ++m)
                for (int n = 0; n < 4; ++n)
                    acc[m][n] = __builtin_amdgcn_mfma_f32_16x16x32_bf16(af[m], bfr[n], acc[m][n], 0, 0, 0);
        }
        __syncthreads();
    }
    #undef LOAD_KT

    int o0 = ot * 128;
    if (ot < 4) {
        bf16* dst = (ot < 2) ? (Qs + (size_t)b * N_ * C_) : (Kt + (size_t)b * N_ * C_);
        for (int m = 0; m < 4; ++m) for (int n = 0; n < 4; ++n) {
            int o = o0 + wc * 64 + n * 16 + (lane & 15);
            float bias = qb[o];
            int row0 = nt * 128 + wr * 64 + m * 16 + (lane >> 4) * 4;
            for (int r = 0; r < 4; ++r)
                dst[(size_t)(row0 + r) * C_ + (o & 255)] = (bf16)(acc[m][n][r] + bias);
        }
    } else {
        bf16* tileE = smem;               // [128][136]
        for (int m = 0; m < 4; ++m) for (int n = 0; n < 4; ++n) {
            int ol = wc * 64 + n * 16 + (lane & 15);
            float bias = qb[o0 + ol];
            int rl0 = wr * 64 + m * 16 + (lane >> 4) * 4;
            for (int r = 0; r < 4; ++r)
                tileE[(size_t)ol * 136 + rl0 + r] = (bf16)(acc[m][n][r] + bias);
        }
        __syncthreads();
        bf16* Vb = Vt + (size_t)b * C_ * N_ + (size_t)(o0 - 512) * N_ + (size_t)nt * 128;
        for (int u = tid; u < 128 * 16; u += 256) {
            int ol = u >> 4, ch = u & 15;
            bf16x8 v = *(const bf16x8*)&tileE[ol * 136 + ch * 8];
            *(bf16x8*)&Vb[(size_t)ol * N_ + ch * 8] = v;
        }
    }
}

// ---------------- kernel 3: fused attention (v6: 4 fat waves) ----------------
// 4 waves x 32 q-rows = 128 q-rows/block; __launch_bounds__(256,1) raises the
// VGPR cap to 512 so the 2x16-row accumulator (128 VGPR) fits WITHOUT spill
// (R4 spilled at the 256 cap with 2 waves/SIMD). Halves per-block LDS traffic
// vs 8 thin waves: 4x64 = 256 b128 reads/tile (~2048 cyc) < MFMA 2483 cyc.
// Grid (32 batch, 8 qb) batch-fastest: XCD-local K/V (R5 win, FETCH 32MB).
// K[64][256] SWZ9 + V[256][64] SWZ7 dbuf via global_load_lds; 1 barrier/tile.
__global__ __launch_bounds__(256, 1) void k_attn(const bf16* __restrict__ Qs,
                                                 const bf16* __restrict__ Kt,
                                                 const bf16* __restrict__ Vt,
                                                 bf16* __restrict__ Ao) {
    extern __shared__ char smem[];
    bf16* kbuf = (bf16*)smem;                  // 2 x 16384 el (64KB)
    bf16* vbuf = (bf16*)(smem + 65536);        // 2 x 16384 el (64KB)
    bf16* pl   = (bf16*)(smem + 131072);       // 128 x 72 el (18KB)
    int b = blockIdx.x, qb = blockIdx.y;
    int tid = threadIdx.x, wid = tid >> 6, lane = tid & 63;
    const bf16* Qb = Qs + (size_t)b * N_ * C_;
    const bf16* Kb = Kt + (size_t)b * N_ * C_;
    const bf16* Vb = Vt + (size_t)b * C_ * N_;
    int q0 = qb * 128;

    // Q: 32 rows/wave as two 16-row m-frags (64 VGPR)
    bf16x8 qf[2][8];
    #pragma unroll
    for (int m = 0; m < 2; ++m) {
        int row = q0 + wid * 32 + m * 16 + (lane & 15);
        const bf16* qr = Qb + (size_t)row * C_ + (lane >> 4) * 8;
        #pragma unroll
        for (int kk = 0; kk < 8; ++kk) qf[m][kk] = *(const bf16x8*)(qr + kk * 32);
    }

    f32x4 oacc[2][16] = {};                    // 128 VGPR
    float mrun[2][4], lrun[2][4];
    #pragma unroll
    for (int m = 0; m < 2; ++m)
        #pragma unroll
        for (int r = 0; r < 4; ++r) { mrun[m][r] = -1e30f; lrun[m][r] = 0.f; }

    // stage tile mt into buffer bi: K (swz9) and V (swz7), source pre-swizzled
    auto stage = [&](int mt, int bi) {
        int m0 = mt * 64;
        bf16* kd = kbuf + bi * 16384;
        bf16* vd = vbuf + bi * 16384;
        #pragma unroll
        for (int j = 0; j < 8; ++j) {
            int chunk = wid * 8 + j;                 // 0..31, wave-uniform
            int el0 = chunk * 512 + lane * 8;        // per-lane linear element
            int krow = el0 >> 8;
            int kcol = (el0 ^ ((krow & 15) << 3)) & 255;
            GLOAD16(Kb + (size_t)(m0 + krow) * C_ + kcol, kd + chunk * 512);
            int vrow = el0 >> 6;
            int vcol = (el0 ^ ((vrow & 7) << 3)) & 63;
            GLOAD16(Vb + (size_t)vrow * N_ + m0 + vcol, vd + chunk * 512);
        }
    };

    stage(0, 0);
    __syncthreads();

    for (int mt = 0; mt < 16; ++mt) {
        int cur = mt & 1;
        if (mt < 15) stage(mt + 1, cur ^ 1);

        const bf16* kc = kbuf + cur * 16384;
        const bf16* vc = vbuf + cur * 16384;

        // QK^T: S[32q x 64kv]
        f32x4 sac[2][4] = {};
        __builtin_amdgcn_s_setprio(1);
        #pragma unroll
        for (int kk = 0; kk < 8; ++kk)
            #pragma unroll
            for (int n = 0; n < 4; ++n) {
                int el = (n * 16 + (lane & 15)) * 256 + kk * 32 + (lane >> 4) * 8;
                bf16x8 bfr = *(const bf16x8*)&kc[SWZ9(el)];
                #pragma unroll
                for (int m = 0; m < 2; ++m)
                    sac[m][n] = __builtin_amdgcn_mfma_f32_16x16x32_bf16(qf[m][kk], bfr, sac[m][n], 0, 0, 0);
            }
        __builtin_amdgcn_s_setprio(0);

        // online softmax with defer-max (THR=8); row = wid*32+m*16+(lane>>4)*4+r
        float mx[2][4];
        bool need = false;
        #pragma unroll
        for (int m = 0; m < 2; ++m)
            #pragma unroll
            for (int r = 0; r < 4; ++r) {
                float mv = fmaxf(fmaxf(sac[m][0][r], sac[m][1][r]),
                                 fmaxf(sac[m][2][r], sac[m][3][r])) * 0.0625f;
                for (int off = 8; off; off >>= 1) mv = fmaxf(mv, __shfl_xor(mv, off));
                mx[m][r] = mv;
                need |= (mv > mrun[m][r] + 8.f);
            }
        if (__any(need)) {
            #pragma unroll
            for (int m = 0; m < 2; ++m)
                #pragma unroll
                for (int r = 0; r < 4; ++r) {
                    float mnew = fmaxf(mrun[m][r], mx[m][r]);
                    float alpha = __expf(mrun[m][r] - mnew);
                    float rsum = 0.f;
                    int prow = (wid * 32 + m * 16 + (lane >> 4) * 4 + r) * 72 + (lane & 15);
                    #pragma unroll
                    for (int n = 0; n < 4; ++n) {
                        float e = __expf(sac[m][n][r] * 0.0625f - mnew);
                        rsum += e;
                        pl[prow + n * 16] = (bf16)e;
                    }
                    for (int off = 8; off; off >>= 1) rsum += __shfl_xor(rsum, off);
                    lrun[m][r] = lrun[m][r] * alpha + rsum;
                    mrun[m][r] = mnew;
                    #pragma unroll
                    for (int c = 0; c < 16; ++c) oacc[m][c][r] *= alpha;
                }
        } else {
            #pragma unroll
            for (int m = 0; m < 2; ++m)
                #pragma unroll
                for (int r = 0; r < 4; ++r) {
                    float rsum = 0.f;
                    int prow = (wid * 32 + m * 16 + (lane >> 4) * 4 + r) * 72 + (lane & 15);
                    #pragma unroll
                    for (int n = 0; n < 4; ++n) {
                        float e = __expf(sac[m][n][r] * 0.0625f - mrun[m][r]);
                        rsum += e;
                        pl[prow + n * 16] = (bf16)e;
                    }
                    for (int off = 8; off; off >>= 1) rsum += __shfl_xor(rsum, off);
                    lrun[m][r] += rsum;
                }
        }

        // PV: O[32q x 256c] += P[32q x 64kv] * V[64kv x 256c]
        // (pl is wave-local: no barrier needed between write and read)
        __builtin_amdgcn_s_setprio(1);
        #pragma unroll
        for (int ks = 0; ks < 2; ++ks) {
            bf16x8 af[2];
            #pragma unroll
            for (int m = 0; m < 2; ++m) {
                int prow = (wid * 32 + m * 16 + (lane & 15)) * 72 + ks * 32 + (lane >> 4) * 8;
                af[m] = *(const bf16x8*)&pl[prow];
            }
            #pragma unroll
            for (int c = 0; c < 16; ++c) {
                int el = (c * 16 + (lane & 15)) * 64 + ks * 32 + (lane >> 4) * 8;
                bf16x8 bfr = *(const bf16x8*)&vc[SWZ7(el)];
                #pragma unroll
                for (int m = 0; m < 2; ++m)
                    oacc[m][c] = __builtin_amdgcn_mfma_f32_16x16x32_bf16(af[m], bfr, oacc[m][c], 0, 0, 0);
            }
        }
        __builtin_amdgcn_s_setprio(0);

        __syncthreads();   // drains tile t+1 loads; frees buf cur for t+2
    }

    #pragma unroll
    for (int m = 0; m < 2; ++m)
        #pragma unroll
        for (int r = 0; r < 4; ++r) {
            float inv = 1.f / lrun[m][r];
            int row = q0 + wid * 32 + m * 16 + (lane >> 4) * 4 + r;
            #pragma unroll
            for (int c = 0; c < 16; ++c)
                Ao[(size_t)b * N_ * C_ + (size_t)row * C_ + c * 16 + (lane & 15)] = (bf16)(oacc[m][c][r] * inv);
        }
}

// ---------------- kernel 4: out proj + bias + residual ----------------
__global__ __launch_bounds__(256) void k_proj(const bf16* __restrict__ Ao,
                                              const bf16* __restrict__ wo,
                                              const float* __restrict__ ob,
                                              const bf16* __restrict__ xn,
                                              float* __restrict__ out) {
    __shared__ bf16 aT[128 * 64];
    __shared__ bf16 bT[128 * 64];
    int nt = blockIdx.x, ot = blockIdx.y, b = blockIdx.z;
    int tid = threadIdx.x, wid = tid >> 6, lane = tid & 63;
    int wr = wid >> 1, wc = wid & 1;
    const bf16* Abase = wo + (size_t)ot * 128 * C_;
    const bf16* Bbase = Ao + (size_t)b * N_ * C_ + (size_t)nt * 128 * C_;

    bf16x8 areg[4], breg[4];
    #define LOAD_KT(kt)                                                            \
        for (int j = 0; j < 4; ++j) {                                              \
            int lin = (j * 256 + tid) * 8;                                         \
            int row = lin >> 6, col = lin & 63;                                    \
            areg[j] = *(const bf16x8*)&Abase[(size_t)row * C_ + (kt) * 64 + col];  \
            breg[j] = *(const bf16x8*)&Bbase[(size_t)row * C_ + (kt) * 64 + col];  \
        }

    f32x4 acc[4][4] = {};
    LOAD_KT(0);
    for (int kt = 0; kt < 4; ++kt) {
        for (int j = 0; j < 4; ++j) {
            int lin = (j * 256 + tid) * 8;
            *(bf16x8*)&aT[SWZ7(lin)] = areg[j];
            *(bf16x8*)&bT[SWZ7(lin)] = breg[j];
        }
        __syncthreads();
        if (kt < 3) { LOAD_KT(kt + 1); }
        for (int kk = 0; kk < 2; ++kk) {
            bf16x8 af[4], bfr[4];
            for (int m = 0; m < 4; ++m) {
                int el = (wr * 64 + m * 16 + (lane & 15)) * 64 + kk * 32 + (lane >> 4) * 8;
                af[m] = *(const bf16x8*)&aT[SWZ7(el)];
            }
            for (int n = 0; n < 4; ++n) {
                int el = (wc * 64 + n * 16 + (lane & 15)) * 64 + kk * 32 + (lane >> 4) * 8;
                bfr[n] = *(const bf16x8*)&bT[SWZ7(el)];
            }
            for (int m = 0; m < 4; ++m)
                for (int n = 0; n < 4; ++n)
                    acc[m][n] = __builtin_amdgcn_mfma_f32_16x16x32_bf16(af[m], bfr[n], acc[m][n], 0, 0, 0);
        }
        __syncthreads();
    }
    #undef LOAD_KT

    for (int m = 0; m < 4; ++m) {
        int o0 = ot * 128 + wr * 64 + m * 16 + (lane >> 4) * 4;
        for (int n = 0; n < 4; ++n) {
            int col = nt * 128 + wc * 64 + n * 16 + (lane & 15);
            for (int r = 0; r < 4; ++r) {
                int o = o0 + r;
                float v = acc[m][n][r] + ob[o] + (float)xn[(size_t)b * C_ * N_ + (size_t)o * N_ + col];
                out[(size_t)b * C_ * N_ + (size_t)o * N_ + col] = v;
            }
        }
    }
}

// ---------------- launch ----------------
extern "C" void kernel_launch(void* const* d_in, const int* in_sizes, int n_in,
                              void* d_out, int out_size, void* d_ws, size_t ws_size,
                              hipStream_t stream) {
    const float* x     = (const float*)d_in[0];
    const float* gn_w  = (const float*)d_in[1];
    const float* gn_b  = (const float*)d_in[2];
    const float* qkv_w = (const float*)d_in[3];
    const float* qkv_b = (const float*)d_in[4];
    const float* out_w = (const float*)d_in[5];
    const float* out_b = (const float*)d_in[6];
    float* out = (float*)d_out;

    char* ws = (char*)d_ws;
    size_t tensor = (size_t)B_ * C_ * N_ * 2;   // 16.78 MB
    bf16* xn  = (bf16*)(ws);
    bf16* xt  = (bf16*)(ws + tensor);
    bf16* Qs  = (bf16*)(ws + 2 * tensor);
    bf16* Kt  = (bf16*)(ws + 3 * tensor);
    bf16* Vt  = (bf16*)(ws + 4 * tensor);
    bf16* Ao  = xt;                              // alias: xt dead after k_qkv
    bf16* qkv_wh = (bf16*)(ws + 5 * tensor);
    bf16* out_wh = (bf16*)(ws + 5 * tensor + (size_t)O3_ * C_ * 2);

    (void)hipFuncSetAttribute(reinterpret_cast<const void*>(&k_attn),
                              hipFuncAttributeMaxDynamicSharedMemorySize, 149504);

    k_convert<<<768, 256, 0, stream>>>(qkv_w, out_w, qkv_wh, out_wh);
    k_gn<<<256, 256, 0, stream>>>(x, gn_w, gn_b, xn, xt);
    k_qkv<<<dim3(8, 6, 32), 256, 0, stream>>>(xt, qkv_wh, qkv_b, Qs, Kt, Vt);
    k_attn<<<dim3(32, 8), 256, 149504, stream>>>(Qs, Kt, Vt, Ao);
    k_proj<<<dim3(8, 2, 32), 256, 0, stream>>>(Ao, out_wh, out_b, xn, out);
}

// Round 8
// 150.006 us; speedup vs baseline: 2.2560x; 2.2560x over previous
//
#include <hip/hip_runtime.h>
#include <hip/hip_bf16.h>

typedef __bf16 bf16;
typedef __bf16 bf16x4 __attribute__((ext_vector_type(4)));
typedef __bf16 bf16x8 __attribute__((ext_vector_type(8)));
typedef float f32x4 __attribute__((ext_vector_type(4)));

#define B_  32
#define C_  256
#define N_  1024
#define G_  8
#define CG_ 32
#define O3_ 768

// LDS XOR swizzles (element-index form). 8-element (16B) chunks preserved.
// 512B rows (256 bf16/row): slot(5b) ^= row&15
#define SWZ9(el) ((el) ^ ((((el) >> 8) & 15) << 3))
// 128B rows (64 bf16/row): slot(3b) ^= row&7
#define SWZ7(el) ((el) ^ ((((el) >> 6) & 7) << 3))

// async global->LDS, 16B per lane. LDS dest must be wave-uniform base (lanes
// auto-scatter base + lane*16); global src is per-lane.
#define GLOAD16(gp, lp)                                                        \
    __builtin_amdgcn_global_load_lds(                                          \
        (const __attribute__((address_space(1))) void*)(gp),                   \
        (__attribute__((address_space(3))) void*)(lp), 16, 0, 0)

// ---------------- kernel 0: weights f32 -> bf16 ----------------
__global__ __launch_bounds__(256) void k_convert(const float* __restrict__ qkv_w,
                                                 const float* __restrict__ out_w,
                                                 bf16* __restrict__ qkv_wh,
                                                 bf16* __restrict__ out_wh) {
    int i = blockIdx.x * 256 + threadIdx.x;
    if (i < O3_ * C_) qkv_wh[i] = (bf16)qkv_w[i];
    if (i < C_ * C_)  out_wh[i] = (bf16)out_w[i];
}

// ---------------- kernel 1: group norm (float4 vectorized) ----------------
__global__ __launch_bounds__(256) void k_gn(const float* __restrict__ x,
                                            const float* __restrict__ w,
                                            const float* __restrict__ bia,
                                            bf16* __restrict__ xn,
                                            bf16* __restrict__ xt) {
    int bg = blockIdx.x;
    int b = bg >> 3, g = bg & 7;
    const float4* xb4 = (const float4*)(x + (size_t)b * C_ * N_ + (size_t)g * CG_ * N_);
    int tid = threadIdx.x;

    float s = 0.f, ss = 0.f;
    for (int i = tid; i < CG_ * N_ / 4; i += 256) {
        float4 v = xb4[i];
        s  += v.x + v.y + v.z + v.w;
        ss += v.x * v.x + v.y * v.y + v.z * v.z + v.w * v.w;
    }
    for (int off = 32; off; off >>= 1) {
        s  += __shfl_down(s, off);
        ss += __shfl_down(ss, off);
    }
    __shared__ float red[8];
    __shared__ float stat[2];
    int wid = tid >> 6, lane = tid & 63;
    if (lane == 0) { red[wid] = s; red[wid + 4] = ss; }
    __syncthreads();
    if (tid == 0) {
        float S  = red[0] + red[1] + red[2] + red[3];
        float SS = red[4] + red[5] + red[6] + red[7];
        float mu = S / (float)(CG_ * N_);
        float var = SS / (float)(CG_ * N_) - mu * mu;
        stat[0] = mu;
        stat[1] = rsqrtf(var + 1e-5f);
    }
    __syncthreads();
    float mu = stat[0], rstd = stat[1];

    __shared__ bf16 tile[256][CG_ + 8];
    for (int nc = 0; nc < N_; nc += 256) {
        for (int i = tid; i < 2048; i += 256) {
            int cl = i >> 6, f = i & 63;
            int c = g * CG_ + cl;
            float sc = rstd * w[c], sh = bia[c] - mu * sc;
            float4 v = xb4[(size_t)cl * 256 + (nc >> 2) + f];
            bf16x4 h = { (bf16)(v.x * sc + sh), (bf16)(v.y * sc + sh),
                         (bf16)(v.z * sc + sh), (bf16)(v.w * sc + sh) };
            *(bf16x4*)(xn + (size_t)b * C_ * N_ + (size_t)c * N_ + nc + f * 4) = h;
            tile[f * 4 + 0][cl] = h[0];
            tile[f * 4 + 1][cl] = h[1];
            tile[f * 4 + 2][cl] = h[2];
            tile[f * 4 + 3][cl] = h[3];
        }
        __syncthreads();
        for (int u = tid; u < 256 * 4; u += 256) {
            int nl = u >> 2, ch = u & 3;
            bf16x8 v = *(const bf16x8*)&tile[nl][ch * 8];
            *(bf16x8*)(xt + (size_t)b * N_ * C_ + (size_t)(nc + nl) * C_ + g * CG_ + ch * 8) = v;
        }
        __syncthreads();
    }
}

// ---------------- kernel 2: QKV GEMM ----------------
__global__ __launch_bounds__(256) void k_qkv(const bf16* __restrict__ xt,
                                             const bf16* __restrict__ wq,
                                             const float* __restrict__ qb,
                                             bf16* __restrict__ Qs,
                                             bf16* __restrict__ Kt,
                                             bf16* __restrict__ Vt) {
    __shared__ bf16 smem[17408];
    bf16* aT = smem;                      // [128][64], swizzled
    bf16* bT = smem + 8192;               // [128][64], swizzled
    int nt = blockIdx.x, ot = blockIdx.y, b = blockIdx.z;
    int tid = threadIdx.x, wid = tid >> 6, lane = tid & 63;
    int wr = wid >> 1, wc = wid & 1;
    const bf16* Ab = xt + (size_t)b * N_ * C_ + (size_t)nt * 128 * C_;
    const bf16* Bb = wq + (size_t)ot * 128 * C_;

    bf16x8 areg[4], breg[4];
    #define LOAD_KT(kt)                                                        \
        for (int j = 0; j < 4; ++j) {                                          \
            int lin = (j * 256 + tid) * 8;                                     \
            int row = lin >> 6, col = lin & 63;                                \
            areg[j] = *(const bf16x8*)&Ab[(size_t)row * C_ + (kt) * 64 + col]; \
            breg[j] = *(const bf16x8*)&Bb[(size_t)row * C_ + (kt) * 64 + col]; \
        }

    f32x4 acc[4][4] = {};
    LOAD_KT(0);
    for (int kt = 0; kt < 4; ++kt) {
        for (int j = 0; j < 4; ++j) {
            int lin = (j * 256 + tid) * 8;
            *(bf16x8*)&aT[SWZ7(lin)] = areg[j];
            *(bf16x8*)&bT[SWZ7(lin)] = breg[j];
        }
        __syncthreads();
        if (kt < 3) { LOAD_KT(kt + 1); }
        for (int kk = 0; kk < 2; ++kk) {
            bf16x8 af[4], bfr[4];
            for (int m = 0; m < 4; ++m) {
                int el = (wr * 64 + m * 16 + (lane & 15)) * 64 + kk * 32 + (lane >> 4) * 8;
                af[m] = *(const bf16x8*)&aT[SWZ7(el)];
            }
            for (int n = 0; n < 4; ++n) {
                int el = (wc * 64 + n * 16 + (lane & 15)) * 64 + kk * 32 + (lane >> 4) * 8;
                bfr[n] = *(const bf16x8*)&bT[SWZ7(el)];
            }
            for (int m = 0; m < 4; ++m)
                for (int n = 0; n < 4; ++n)
                    acc[m][n] = __builtin_amdgcn_mfma_f32_16x16x32_bf16(af[m], bfr[n], acc[m][n], 0, 0, 0);
        }
        __syncthreads();
    }
    #undef LOAD_KT

    int o0 = ot * 128;
    if (ot < 4) {
        bf16* dst = (ot < 2) ? (Qs + (size_t)b * N_ * C_) : (Kt + (size_t)b * N_ * C_);
        for (int m = 0; m < 4; ++m) for (int n = 0; n < 4; ++n) {
            int o = o0 + wc * 64 + n * 16 + (lane & 15);
            float bias = qb[o];
            int row0 = nt * 128 + wr * 64 + m * 16 + (lane >> 4) * 4;
            for (int r = 0; r < 4; ++r)
                dst[(size_t)(row0 + r) * C_ + (o & 255)] = (bf16)(acc[m][n][r] + bias);
        }
    } else {
        bf16* tileE = smem;               // [128][136]
        for (int m = 0; m < 4; ++m) for (int n = 0; n < 4; ++n) {
            int ol = wc * 64 + n * 16 + (lane & 15);
            float bias = qb[o0 + ol];
            int rl0 = wr * 64 + m * 16 + (lane >> 4) * 4;
            for (int r = 0; r < 4; ++r)
                tileE[(size_t)ol * 136 + rl0 + r] = (bf16)(acc[m][n][r] + bias);
        }
        __syncthreads();
        bf16* Vb = Vt + (size_t)b * C_ * N_ + (size_t)(o0 - 512) * N_ + (size_t)nt * 128;
        for (int u = tid; u < 128 * 16; u += 256) {
            int ol = u >> 4, ch = u & 15;
            bf16x8 v = *(const bf16x8*)&tileE[ol * 136 + ch * 8];
            *(bf16x8*)&Vb[(size_t)ol * N_ + ch * 8] = v;
        }
    }
}

// ---------------- kernel 3: fused attention (v7b: 2 blocks/CU, LDS size fixed) ----------------
// 4 waves x 16 q-rows = 64 q-rows/block; KVBLK=32; LDS 70656 B -> 2 blocks/CU
// (2 x 70656 = 141312 <= 163840). Grid (32 batch, 16 qb) batch-fastest;
// co-resident blocks share the same batch -> K/V L2-hot; barrier-independent
// blocks overlap pipe phases (m114).
// K[32][256] SWZ9 (gload_lds, pre-swizzled src). V packed as ch-pair rows:
// el(ch,kv) = (ch>>1)*64 + (ch&1)*32 + kv, SWZ7. P rows padded to 40 el.
__global__ __launch_bounds__(256, 2) void k_attn(const bf16* __restrict__ Qs,
                                                 const bf16* __restrict__ Kt,
                                                 const bf16* __restrict__ Vt,
                                                 bf16* __restrict__ Ao) {
    extern __shared__ char smem[];
    bf16* kbuf = (bf16*)smem;                  // 2 x 8192 el (32KB)
    bf16* vbuf = (bf16*)(smem + 32768);        // 2 x 8192 el (32KB)
    bf16* pl   = (bf16*)(smem + 65536);        // 64 x 40 el = 5120 B
    int b = blockIdx.x, qb = blockIdx.y;
    int tid = threadIdx.x, wid = tid >> 6, lane = tid & 63;
    const bf16* Qb = Qs + (size_t)b * N_ * C_;
    const bf16* Kb = Kt + (size_t)b * N_ * C_;
    const bf16* Vb = Vt + (size_t)b * C_ * N_;
    int q0 = qb * 64;

    bf16x8 qf[8];
    {
        int row = q0 + wid * 16 + (lane & 15);
        const bf16* qr = Qb + (size_t)row * C_ + (lane >> 4) * 8;
        #pragma unroll
        for (int kk = 0; kk < 8; ++kk) qf[kk] = *(const bf16x8*)(qr + kk * 32);
    }

    f32x4 oacc[16] = {};
    float mrun[4], lrun[4];
    for (int r = 0; r < 4; ++r) { mrun[r] = -1e30f; lrun[r] = 0.f; }

    // stage tile mt into buffer bi. dest linear; src = inverse-swizzled global.
    auto stage = [&](int mt, int bi) {
        int m0 = mt * 32;
        bf16* kd = kbuf + bi * 8192;
        bf16* vd = vbuf + bi * 8192;
        #pragma unroll
        for (int j = 0; j < 4; ++j) {
            int chunk = wid * 4 + j;                 // 0..15, wave-uniform
            int d = chunk * 512 + lane * 8;          // linear dest element
            int ek = SWZ9(d);                        // involution
            int krow = ek >> 8, kcol = ek & 255;
            GLOAD16(Kb + (size_t)(m0 + krow) * C_ + kcol, kd + chunk * 512);
            int ev = SWZ7(d);
            int kv = ev & 31;
            int ch = ((ev >> 6) << 1) | ((ev >> 5) & 1);
            GLOAD16(Vb + (size_t)ch * N_ + m0 + kv, vd + chunk * 512);
        }
    };

    stage(0, 0);
    __syncthreads();

    for (int mt = 0; mt < 32; ++mt) {
        int cur = mt & 1;
        if (mt < 31) stage(mt + 1, cur ^ 1);

        const bf16* kc = kbuf + cur * 8192;
        const bf16* vc = vbuf + cur * 8192;

        // QK^T: S[16q x 32kv]
        f32x4 sac[2] = {};
        __builtin_amdgcn_s_setprio(1);
        #pragma unroll
        for (int kk = 0; kk < 8; ++kk)
            #pragma unroll
            for (int n = 0; n < 2; ++n) {
                int el = (n * 16 + (lane & 15)) * 256 + kk * 32 + (lane >> 4) * 8;
                bf16x8 bfr = *(const bf16x8*)&kc[SWZ9(el)];
                sac[n] = __builtin_amdgcn_mfma_f32_16x16x32_bf16(qf[kk], bfr, sac[n], 0, 0, 0);
            }
        __builtin_amdgcn_s_setprio(0);

        // online softmax with defer-max (THR=8); row owned by (lane>>4, r)
        float mx[4];
        bool need = false;
        #pragma unroll
        for (int r = 0; r < 4; ++r) {
            float mv = fmaxf(sac[0][r], sac[1][r]) * 0.0625f;
            for (int off = 8; off; off >>= 1) mv = fmaxf(mv, __shfl_xor(mv, off));
            mx[r] = mv;
            need |= (mv > mrun[r] + 8.f);
        }
        if (__any(need)) {
            #pragma unroll
            for (int r = 0; r < 4; ++r) {
                float mnew = fmaxf(mrun[r], mx[r]);
                float alpha = __expf(mrun[r] - mnew);
                float rsum = 0.f;
                int prow = (wid * 16 + (lane >> 4) * 4 + r) * 40 + (lane & 15);
                #pragma unroll
                for (int n = 0; n < 2; ++n) {
                    float e = __expf(sac[n][r] * 0.0625f - mnew);
                    rsum += e;
                    pl[prow + n * 16] = (bf16)e;
                }
                for (int off = 8; off; off >>= 1) rsum += __shfl_xor(rsum, off);
                lrun[r] = lrun[r] * alpha + rsum;
                mrun[r] = mnew;
                #pragma unroll
                for (int c = 0; c < 16; ++c) oacc[c][r] *= alpha;
            }
        } else {
            #pragma unroll
            for (int r = 0; r < 4; ++r) {
                float rsum = 0.f;
                int prow = (wid * 16 + (lane >> 4) * 4 + r) * 40 + (lane & 15);
                #pragma unroll
                for (int n = 0; n < 2; ++n) {
                    float e = __expf(sac[n][r] * 0.0625f - mrun[r]);
                    rsum += e;
                    pl[prow + n * 16] = (bf16)e;
                }
                for (int off = 8; off; off >>= 1) rsum += __shfl_xor(rsum, off);
                lrun[r] += rsum;
            }
        }

        // PV: O[16q x 256c] += P[16q x 32kv] * V[32kv x 256c]
        // (pl is wave-local: no barrier between write and read)
        __builtin_amdgcn_s_setprio(1);
        bf16x8 af = *(const bf16x8*)&pl[(wid * 16 + (lane & 15)) * 40 + (lane >> 4) * 8];
        #pragma unroll
        for (int c = 0; c < 16; ++c) {
            int ch = c * 16 + (lane & 15);
            int e = (ch >> 1) * 64 + (ch & 1) * 32 + (lane >> 4) * 8;
            bf16x8 bfr = *(const bf16x8*)&vc[SWZ7(e)];
            oacc[c] = __builtin_amdgcn_mfma_f32_16x16x32_bf16(af, bfr, oacc[c], 0, 0, 0);
        }
        __builtin_amdgcn_s_setprio(0);

        __syncthreads();   // drains tile t+1 loads; frees buf cur for t+2
    }

    #pragma unroll
    for (int r = 0; r < 4; ++r) {
        float inv = 1.f / lrun[r];
        int row = q0 + wid * 16 + (lane >> 4) * 4 + r;
        #pragma unroll
        for (int c = 0; c < 16; ++c)
            Ao[(size_t)b * N_ * C_ + (size_t)row * C_ + c * 16 + (lane & 15)] = (bf16)(oacc[c][r] * inv);
    }
}

// ---------------- kernel 4: out proj + bias + residual ----------------
__global__ __launch_bounds__(256) void k_proj(const bf16* __restrict__ Ao,
                                              const bf16* __restrict__ wo,
                                              const float* __restrict__ ob,
                                              const bf16* __restrict__ xn,
                                              float* __restrict__ out) {
    __shared__ bf16 aT[128 * 64];
    __shared__ bf16 bT[128 * 64];
    int nt = blockIdx.x, ot = blockIdx.y, b = blockIdx.z;
    int tid = threadIdx.x, wid = tid >> 6, lane = tid & 63;
    int wr = wid >> 1, wc = wid & 1;
    const bf16* Abase = wo + (size_t)ot * 128 * C_;
    const bf16* Bbase = Ao + (size_t)b * N_ * C_ + (size_t)nt * 128 * C_;

    bf16x8 areg[4], breg[4];
    #define LOAD_KT(kt)                                                            \
        for (int j = 0; j < 4; ++j) {                                              \
            int lin = (j * 256 + tid) * 8;                                         \
            int row = lin >> 6, col = lin & 63;                                    \
            areg[j] = *(const bf16x8*)&Abase[(size_t)row * C_ + (kt) * 64 + col];  \
            breg[j] = *(const bf16x8*)&Bbase[(size_t)row * C_ + (kt) * 64 + col];  \
        }

    f32x4 acc[4][4] = {};
    LOAD_KT(0);
    for (int kt = 0; kt < 4; ++kt) {
        for (int j = 0; j < 4; ++j) {
            int lin = (j * 256 + tid) * 8;
            *(bf16x8*)&aT[SWZ7(lin)] = areg[j];
            *(bf16x8*)&bT[SWZ7(lin)] = breg[j];
        }
        __syncthreads();
        if (kt < 3) { LOAD_KT(kt + 1); }
        for (int kk = 0; kk < 2; ++kk) {
            bf16x8 af[4], bfr[4];
            for (int m = 0; m < 4; ++m) {
                int el = (wr * 64 + m * 16 + (lane & 15)) * 64 + kk * 32 + (lane >> 4) * 8;
                af[m] = *(const bf16x8*)&aT[SWZ7(el)];
            }
            for (int n = 0; n < 4; ++n) {
                int el = (wc * 64 + n * 16 + (lane & 15)) * 64 + kk * 32 + (lane >> 4) * 8;
                bfr[n] = *(const bf16x8*)&bT[SWZ7(el)];
            }
            for (int m = 0; m < 4; ++m)
                for (int n = 0; n < 4; ++n)
                    acc[m][n] = __builtin_amdgcn_mfma_f32_16x16x32_bf16(af[m], bfr[n], acc[m][n], 0, 0, 0);
        }
        __syncthreads();
    }
    #undef LOAD_KT

    for (int m = 0; m < 4; ++m) {
        int o0 = ot * 128 + wr * 64 + m * 16 + (lane >> 4) * 4;
        for (int n = 0; n < 4; ++n) {
            int col = nt * 128 + wc * 64 + n * 16 + (lane & 15);
            for (int r = 0; r < 4; ++r) {
                int o = o0 + r;
                float v = acc[m][n][r] + ob[o] + (float)xn[(size_t)b * C_ * N_ + (size_t)o * N_ + col];
                out[(size_t)b * C_ * N_ + (size_t)o * N_ + col] = v;
            }
        }
    }
}

// ---------------- launch ----------------
extern "C" void kernel_launch(void* const* d_in, const int* in_sizes, int n_in,
                              void* d_out, int out_size, void* d_ws, size_t ws_size,
                              hipStream_t stream) {
    const float* x     = (const float*)d_in[0];
    const float* gn_w  = (const float*)d_in[1];
    const float* gn_b  = (const float*)d_in[2];
    const float* qkv_w = (const float*)d_in[3];
    const float* qkv_b = (const float*)d_in[4];
    const float* out_w = (const float*)d_in[5];
    const float* out_b = (const float*)d_in[6];
    float* out = (float*)d_out;

    char* ws = (char*)d_ws;
    size_t tensor = (size_t)B_ * C_ * N_ * 2;   // 16.78 MB
    bf16* xn  = (bf16*)(ws);
    bf16* xt  = (bf16*)(ws + tensor);
    bf16* Qs  = (bf16*)(ws + 2 * tensor);
    bf16* Kt  = (bf16*)(ws + 3 * tensor);
    bf16* Vt  = (bf16*)(ws + 4 * tensor);
    bf16* Ao  = xt;                              // alias: xt dead after k_qkv
    bf16* qkv_wh = (bf16*)(ws + 5 * tensor);
    bf16* out_wh = (bf16*)(ws + 5 * tensor + (size_t)O3_ * C_ * 2);

    (void)hipFuncSetAttribute(reinterpret_cast<const void*>(&k_attn),
                              hipFuncAttributeMaxDynamicSharedMemorySize, 70656);

    k_convert<<<768, 256, 0, stream>>>(qkv_w, out_w, qkv_wh, out_wh);
    k_gn<<<256, 256, 0, stream>>>(x, gn_w, gn_b, xn, xt);
    k_qkv<<<dim3(8, 6, 32), 256, 0, stream>>>(xt, qkv_wh, qkv_b, Qs, Kt, Vt);
    k_attn<<<dim3(32, 16), 256, 70656, stream>>>(Qs, Kt, Vt, Ao);
    k_proj<<<dim3(8, 2, 32), 256, 0, stream>>>(Ao, out_wh, out_b, xn, out);
}